// Round 11
// baseline (3414.997 us; speedup 1.0000x reference)
//
#include <hip/hip_runtime.h>

#define C 128
#define LDSPAD 136  // padded LDS row stride (ushorts)
#define CAP 64      // padded-CSR slots per node (mean deg 20, Poisson tail < 1e-13)

typedef unsigned int uint;
typedef unsigned short ushort;
typedef __attribute__((ext_vector_type(8))) short bf16x8;
typedef __attribute__((ext_vector_type(4))) float f32x4;

__device__ __forceinline__ float bf_lo(uint u) { return __uint_as_float(u << 16); }
__device__ __forceinline__ float bf_hi(uint u) { return __uint_as_float(u & 0xffff0000u); }
__device__ __forceinline__ uint f2bf(float f) {
  uint u = __float_as_uint(f);
  return (u + 0x7fffu + ((u >> 16) & 1u)) >> 16;  // RNE, no NaN inputs
}

struct Params {
  const int* x;
  const float* emb;
  const float* ln_g; const float* ln_b;
  const int* src1; const int* dst1;
  const int* src2; const int* dst2;
  const float* Wl1; const float* Wr1; const float* Wl2; const float* Wr2;
  const float* bl1; const float* bl2;
  ushort* embh; ushort* h0; ushort* h1; ushort* wb;
  int* cnt1; int* slots1; int* cnt2; int* slots2;
  uint* ctrl;      // [ticket @0][done0 @64][done1 @128][done2 @192] (uints)
  int4* zbase; int nz4;
  float* out;
  int n0, e1, e2, n1, n2, leafN4;
  int K0, K1a, K1b, K2, K3;
};

__device__ __forceinline__ void spin_until(uint* ctr, uint target) {
  uint v = __hip_atomic_load(ctr, __ATOMIC_ACQUIRE, __HIP_MEMORY_SCOPE_AGENT);
  while (v < target) {
    __builtin_amdgcn_s_sleep(4);  // constant immediate required by ISA
    v = __hip_atomic_load(ctr, __ATOMIC_ACQUIRE, __HIP_MEMORY_SCOPE_AGENT);
  }
}

// ---------------- single work-queue kernel ----------------
__global__ __launch_bounds__(512, 6) void k_main(Params p) {
  __shared__ ushort smean[16 * LDSPAD];
  __shared__ uint s_ticket;
  const int tid = threadIdx.x;
  const int lane = tid & 63;
  const int wave = tid >> 6;
  const int TOTAL = p.K0 + p.K1a + p.K1b + p.K2 + p.K3;
  const int W_ELEMS = C * C;

  for (;;) {
    if (tid == 0)
      s_ticket = __hip_atomic_fetch_add(&p.ctrl[0], 1u, __ATOMIC_RELAXED,
                                        __HIP_MEMORY_SCOPE_AGENT);
    __syncthreads();
    int t = (int)s_ticket;
    __syncthreads();  // allow s_ticket reuse next iteration
    if (t >= TOTAL) return;

    uint* doneCtr;  // counter this item increments when finished (nullptr for conv2)
    if (t < p.K0) {
      // ======== Phase 0 item: prep (convert emb+weights to bf16, zero cnt) ========
      const int CH = 2048;
      int U = p.leafN4 + 4 * (W_ELEMS / 4) + p.nz4;
      int lo = t * CH;
      int hi = min(lo + CH, U);
      for (int u = lo + tid; u < hi; u += 512) {
        if (u < p.leafN4) {
          float4 f = ((const float4*)p.emb)[u];
          ushort4 o = {(ushort)f2bf(f.x), (ushort)f2bf(f.y), (ushort)f2bf(f.z), (ushort)f2bf(f.w)};
          ((ushort4*)p.embh)[u] = o;
        } else if (u < p.leafN4 + 4 * (W_ELEMS / 4)) {
          int v = u - p.leafN4;
          int m = v >> 12;        // W_ELEMS/4 = 4096 per matrix
          int j = v & 4095;
          const float4* w = (m == 0) ? (const float4*)p.Wl1
                          : (m == 1) ? (const float4*)p.Wr1
                          : (m == 2) ? (const float4*)p.Wl2
                                     : (const float4*)p.Wr2;
          float4 f = w[j];
          ushort4 o = {(ushort)f2bf(f.x), (ushort)f2bf(f.y), (ushort)f2bf(f.z), (ushort)f2bf(f.w)};
          ((ushort4*)p.wb)[v] = o;
        } else {
          int z = u - p.leafN4 - 4 * (W_ELEMS / 4);
          int4 zz = {0, 0, 0, 0};
          p.zbase[z] = zz;
        }
      }
      doneCtr = &p.ctrl[64];
    } else if (t < p.K0 + p.K1a) {
      // ======== Phase 1a item: padded-CSR bucket, 4096 edges ========
      if (tid == 0) spin_until(&p.ctrl[64], (uint)p.K0);
      __syncthreads();
      int base = (t - p.K0) * 4096;
      int etot = p.e1 + p.e2;
#pragma unroll
      for (int r = 0; r < 8; ++r) {
        int i = base + r * 512 + tid;
        if (i < p.e1) {
          int d = p.dst1[i];
          int pos = atomicAdd(&p.cnt1[d], 1);
          if (pos < CAP) p.slots1[d * CAP + pos] = p.src1[i];
        } else if (i < etot) {
          int j = i - p.e1;
          int d = p.dst2[j];
          int pos = atomicAdd(&p.cnt2[d], 1);
          if (pos < CAP) p.slots2[d * CAP + pos] = p.src2[j];
        }
      }
      doneCtr = &p.ctrl[128];
    } else if (t < p.K0 + p.K1a + p.K1b) {
      // ======== Phase 1b item: embed+LN+ReLU, 8 nodes (1 per wave) ========
      if (tid == 0) spin_until(&p.ctrl[64], (uint)p.K0);
      __syncthreads();
      int node = (t - p.K0 - p.K1a) * 8 + wave;
      if (node < p.n0) {
        int grp = lane >> 5, sub = lane & 31;
        int xv = p.x[(size_t)node * 16 + (lane & 15)];
        float s0 = 0.f, s1 = 0.f, s2 = 0.f, s3 = 0.f;
#pragma unroll
        for (int w = 0; w < 16; w += 2) {
          int tok = __shfl(xv, w + grp, 64);
          uint2 u = ((const uint2*)(p.embh + (size_t)tok * C))[sub];
          s0 += bf_lo(u.x); s1 += bf_hi(u.x); s2 += bf_lo(u.y); s3 += bf_hi(u.y);
        }
        s0 += __shfl_xor(s0, 32, 64);
        s1 += __shfl_xor(s1, 32, 64);
        s2 += __shfl_xor(s2, 32, 64);
        s3 += __shfl_xor(s3, 32, 64);
        float red = s0 + s1 + s2 + s3;
#pragma unroll
        for (int off = 16; off; off >>= 1) red += __shfl_xor(red, off, 64);
        float mu = red * (1.f / C);
        float c0 = s0 - mu, c1 = s1 - mu, c2 = s2 - mu, c3 = s3 - mu;
        float sq = c0 * c0 + c1 * c1 + c2 * c2 + c3 * c3;
#pragma unroll
        for (int off = 16; off; off >>= 1) sq += __shfl_xor(sq, off, 64);
        float rs = rsqrtf(sq * (1.f / C) + 1e-5f);
        float4 gg = ((const float4*)p.ln_g)[sub];
        float4 bb = ((const float4*)p.ln_b)[sub];
        float o0 = fmaxf(c0 * rs * gg.x + bb.x, 0.f);
        float o1 = fmaxf(c1 * rs * gg.y + bb.y, 0.f);
        float o2 = fmaxf(c2 * rs * gg.z + bb.z, 0.f);
        float o3 = fmaxf(c3 * rs * gg.w + bb.w, 0.f);
        if (grp == 0) {
          ushort4 o = {(ushort)f2bf(o0), (ushort)f2bf(o1), (ushort)f2bf(o2), (ushort)f2bf(o3)};
          ((ushort4*)(p.h0 + (size_t)node * C))[sub] = o;
        }
      }
      doneCtr = &p.ctrl[128];
    } else {
      // ======== Phase 2/3 item: fused conv tile (16 nodes) ========
      bool isC1 = t < p.K0 + p.K1a + p.K1b + p.K2;
      int tile = isC1 ? (t - p.K0 - p.K1a - p.K1b) : (t - p.K0 - p.K1a - p.K1b - p.K2);
      int ntgt = isC1 ? p.n1 : p.n2;
      const int* cntArr = isC1 ? p.cnt1 : p.cnt2;
      const int* slots = isC1 ? p.slots1 : p.slots2;
      const ushort* h = isC1 ? p.h0 : p.h1;
      const ushort* Wlb = isC1 ? p.wb : p.wb + 2 * W_ELEMS;
      const ushort* Wrb = isC1 ? p.wb + W_ELEMS : p.wb + 3 * W_ELEMS;
      const float* bl = isC1 ? p.bl1 : p.bl2;
      if (tid == 0) {
        if (isC1) spin_until(&p.ctrl[128], (uint)(p.K1a + p.K1b));
        else      spin_until(&p.ctrl[192], (uint)p.K2);
      }
      __syncthreads();
      int grp = lane >> 5, sub = lane & 31;
      int mbase = tile * 16;
      int nl = wave * 2 + grp;
      int node = mbase + nl;
      // ---- Phase A: half-wave per node aggregate -> smean ----
      int truecnt = (node < ntgt) ? cntArr[node] : 0;
      int cnt = min(truecnt, CAP);
      const int* sl = slots + (size_t)(node < ntgt ? node : 0) * CAP;
      int ev = (sub < cnt) ? sl[sub] : 0;
      int ev2 = (sub + 32 < cnt) ? sl[sub + 32] : 0;
      int dmax = max(cnt, __shfl_xor(cnt, 32, 64));
      int half = grp * 32;
      float s0 = 0.f, s1 = 0.f, s2 = 0.f, s3 = 0.f;
      for (int d = 0; d < dmax; d += 8) {
#pragma unroll
        for (int k = 0; k < 8; ++k) {
          int dk = d + k;
          int e = (dk < 32) ? __shfl(ev, half + dk, 64) : __shfl(ev2, half + dk - 32, 64);
          uint2 u = ((const uint2*)(h + (size_t)e * C))[sub];
          uint msk = (dk < cnt) ? 0xffffffffu : 0u;
          u.x &= msk; u.y &= msk;
          s0 += bf_lo(u.x); s1 += bf_hi(u.x); s2 += bf_lo(u.y); s3 += bf_hi(u.y);
        }
      }
      float sc = 1.f / (float)max(truecnt, 1);
      ushort4 o = {(ushort)f2bf(s0 * sc), (ushort)f2bf(s1 * sc),
                   (ushort)f2bf(s2 * sc), (ushort)f2bf(s3 * sc)};
      *(ushort4*)(smean + nl * LDSPAD + sub * 4) = o;
      __syncthreads();
      // ---- Phase B: MFMA combine ----
      int r16 = lane & 15;
      int quad = lane >> 4;
      int koff = quad * 8;
      bf16x8 am[4], ah[4];
      int hr = min(mbase + r16, ntgt - 1);
      const ushort* hrow = h + (size_t)hr * C;
#pragma unroll
      for (int kc = 0; kc < 4; ++kc) {
        am[kc] = *(const bf16x8*)(smean + r16 * LDSPAD + kc * 32 + koff);
        ah[kc] = *(const bf16x8*)(hrow + kc * 32 + koff);
      }
      int nbase = wave * 16;
      float bias = bl[nbase + r16];
      f32x4 acc = {bias, bias, bias, bias};
      const ushort* wlrow = Wlb + (size_t)(nbase + r16) * C;
      const ushort* wrrow = Wrb + (size_t)(nbase + r16) * C;
#pragma unroll
      for (int kc = 0; kc < 4; ++kc) {
        bf16x8 wl = *(const bf16x8*)(wlrow + kc * 32 + koff);
        acc = __builtin_amdgcn_mfma_f32_16x16x32_bf16(am[kc], wl, acc, 0, 0, 0);
        bf16x8 wr = *(const bf16x8*)(wrrow + kc * 32 + koff);
        acc = __builtin_amdgcn_mfma_f32_16x16x32_bf16(ah[kc], wr, acc, 0, 0, 0);
      }
#pragma unroll
      for (int r = 0; r < 4; ++r) {
        int row = mbase + quad * 4 + r;
        if (row < ntgt) {
          float v = acc[r];
          if (isC1) {
            v = fmaxf(v, 0.f);
            p.h1[(size_t)row * C + nbase + r16] = (ushort)f2bf(v);
          } else {
            p.out[(size_t)row * C + nbase + r16] = v;
          }
        }
      }
      doneCtr = isC1 ? &p.ctrl[192] : nullptr;
    }
    // ---- item complete: publish ----
    __threadfence();
    __syncthreads();
    if (tid == 0 && doneCtr)
      __hip_atomic_fetch_add(doneCtr, 1u, __ATOMIC_RELEASE, __HIP_MEMORY_SCOPE_AGENT);
  }
}

extern "C" void kernel_launch(void* const* d_in, const int* in_sizes, int n_in,
                              void* d_out, int out_size, void* d_ws, size_t ws_size,
                              hipStream_t stream) {
  Params p;
  p.x    = (const int*)d_in[0];
  p.src1 = (const int*)d_in[1];
  p.dst1 = (const int*)d_in[2];
  p.src2 = (const int*)d_in[3];
  p.dst2 = (const int*)d_in[4];
  p.emb  = (const float*)d_in[7];
  p.ln_g = (const float*)d_in[8];
  p.ln_b = (const float*)d_in[9];
  p.Wl1  = (const float*)d_in[10];
  p.bl1  = (const float*)d_in[11];
  p.Wr1  = (const float*)d_in[12];
  p.Wl2  = (const float*)d_in[13];
  p.bl2  = (const float*)d_in[14];
  p.Wr2  = (const float*)d_in[15];

  p.n0 = in_sizes[0] / 16;   // 100000
  p.e1 = in_sizes[1];        // 500000
  p.e2 = in_sizes[3];        // 100000
  p.n1 = 25000;
  p.n2 = 5000;
  const int leafElems = in_sizes[7];  // 50000*128
  p.leafN4 = leafElems / 4;
  const int W_ELEMS = C * C;

  char* ws = (char*)d_ws;
  size_t off = 0;
  auto alloc = [&](size_t bytes) {
    char* ptr = ws + off;
    off += (bytes + 255) & ~(size_t)255;
    return ptr;
  };
  p.embh   = (ushort*)alloc((size_t)leafElems * 2);     // 12.8 MB
  p.h0     = (ushort*)alloc((size_t)p.n0 * C * 2);      // 25.6 MB
  p.h1     = (ushort*)alloc((size_t)p.n1 * C * 2);      //  6.4 MB
  p.wb     = (ushort*)alloc((size_t)4 * W_ELEMS * 2);   // Wl1|Wr1|Wl2|Wr2
  p.slots1 = (int*)alloc((size_t)p.n1 * CAP * 4);       //  6.4 MB
  p.slots2 = (int*)alloc((size_t)p.n2 * CAP * 4);       //  1.28 MB
  char* zbase = ws + off;  // zeroed by phase 0
  p.cnt1   = (int*)alloc((size_t)p.n1 * 4);
  p.cnt2   = (int*)alloc((size_t)p.n2 * 4);
  size_t zbytes = (size_t)((ws + off) - zbase);
  p.zbase = (int4*)zbase;
  p.nz4 = (int)(zbytes / 16);
  p.ctrl = (uint*)alloc(256 * 4);  // ticket/done0/done1/done2 (64-uint stride)
  p.out = (float*)d_out;

  // item counts
  {
    const int CH = 2048;
    int U = p.leafN4 + 4 * (W_ELEMS / 4) + p.nz4;
    p.K0 = (U + CH - 1) / CH;
  }
  p.K1a = (p.e1 + p.e2 + 4095) / 4096;
  p.K1b = (p.n0 + 7) / 8;
  p.K2 = (p.n1 + 15) / 16;
  p.K3 = (p.n2 + 15) / 16;
  int TOTAL = p.K0 + p.K1a + p.K1b + p.K2 + p.K3;

  // zero the control block (ticket + done counters)
  (void)hipMemsetAsync(p.ctrl, 0, 256 * sizeof(uint), stream);

  k_main<<<TOTAL, 512, 0, stream>>>(p);
}

// Round 12
// 321.205 us; speedup vs baseline: 10.6318x; 10.6318x over previous
//
#include <hip/hip_runtime.h>

#define C 128
#define LDSPAD 136  // padded LDS row stride (ushorts)
#define CAP 64      // padded-CSR slots per node (mean deg 20, Poisson tail < 1e-13)
#define NLEAF 8     // barrier leaf counters (each on own 256B line)

typedef unsigned int uint;
typedef unsigned short ushort;
typedef __attribute__((ext_vector_type(8))) short bf16x8;
typedef __attribute__((ext_vector_type(4))) float f32x4;

__device__ __forceinline__ float bf_lo(uint u) { return __uint_as_float(u << 16); }
__device__ __forceinline__ float bf_hi(uint u) { return __uint_as_float(u & 0xffff0000u); }
__device__ __forceinline__ uint f2bf(float f) {
  uint u = __float_as_uint(f);
  return (u + 0x7fffu + ((u >> 16) & 1u)) >> 16;  // RNE, no NaN inputs
}

struct Params {
  const int* x;
  const float* emb;
  const float* ln_g; const float* ln_b;
  const int* src1; const int* dst1;
  const int* src2; const int* dst2;
  const float* Wl1; const float* Wr1; const float* Wl2; const float* Wr2;
  const float* bl1; const float* bl2;
  ushort* embh; ushort* h0; ushort* h1; ushort* wb;
  int* cnt1; int* slots1; int* cnt2; int* slots2;
  uint* ctrl;     // NLEAF leaf counters (stride 64 uints) + rel at [NLEAF<<6]
  int4* zbase; int nz4;
  float* out;
  int n0, e1, e2, n1, n2, leafN4;
};

// ---- grid barrier: RELAXED polling (LLC reads, no invalidate), ONE acquire at exit ----
// Producer visibility: __threadfence (L2 writeback) before arrival.
// Consumer freshness: single ACQUIRE load (one buffer_inv) after spin exits.
__device__ __forceinline__ void grid_barrier(uint* leaves, uint* rel, int barIdx, int nblk) {
  __syncthreads();  // all block stores complete (vmcnt drained)
  if (threadIdx.x == 0) {
    __threadfence();  // write back this XCD's dirty L2 -> LLC
    __hip_atomic_fetch_add(&leaves[(blockIdx.x & (NLEAF - 1)) << 6], 1u,
                           __ATOMIC_RELAXED, __HIP_MEMORY_SCOPE_AGENT);
    uint target = (uint)nblk * (uint)(barIdx + 1);
    if (blockIdx.x == 0) {
      uint s;
      do {
        __builtin_amdgcn_s_sleep(8);
        s = 0;
#pragma unroll
        for (int l = 0; l < NLEAF; ++l)
          s += __hip_atomic_load(&leaves[l << 6], __ATOMIC_RELAXED, __HIP_MEMORY_SCOPE_AGENT);
      } while (s < target);
      __hip_atomic_store(rel, (uint)(barIdx + 1), __ATOMIC_RELEASE, __HIP_MEMORY_SCOPE_AGENT);
    } else {
      uint v;
      do {
        __builtin_amdgcn_s_sleep(16);
        v = __hip_atomic_load(rel, __ATOMIC_RELAXED, __HIP_MEMORY_SCOPE_AGENT);
      } while (v < (uint)(barIdx + 1));
    }
    (void)__hip_atomic_load(rel, __ATOMIC_ACQUIRE, __HIP_MEMORY_SCOPE_AGENT);  // one inv
  }
  __syncthreads();
}

// ---- conv tile phase (R8/R9's verified code) ----
template <bool RELU, bool BF16OUT>
__device__ __forceinline__ void conv_phase(
    const int* __restrict__ cntArr, const int* __restrict__ slots,
    const ushort* __restrict__ h, const ushort* __restrict__ Wlb,
    const float* __restrict__ bl, const ushort* __restrict__ Wrb,
    void* __restrict__ outp, int ntgt, ushort* smean) {
  int wave = threadIdx.x >> 6;
  int lane = threadIdx.x & 63;
  int grp = lane >> 5, sub = lane & 31;
  int r16 = lane & 15;
  int quad = lane >> 4;
  int koff = quad * 8;
  int ntiles = (ntgt + 15) >> 4;
  for (int t = blockIdx.x; t < ntiles; t += gridDim.x) {
    int mbase = t * 16;
    int nl = wave * 2 + grp;
    int node = mbase + nl;
    __syncthreads();  // protect smean from previous tile's readers
    int truecnt = (node < ntgt) ? cntArr[node] : 0;
    int cnt = min(truecnt, CAP);
    const int* sl = slots + (size_t)(node < ntgt ? node : 0) * CAP;
    int ev = (sub < cnt) ? sl[sub] : 0;
    int ev2 = (sub + 32 < cnt) ? sl[sub + 32] : 0;
    int dmax = max(cnt, __shfl_xor(cnt, 32, 64));
    int half = grp * 32;
    float s0 = 0.f, s1 = 0.f, s2 = 0.f, s3 = 0.f;
    for (int d = 0; d < dmax; d += 8) {
#pragma unroll
      for (int k = 0; k < 8; ++k) {
        int dk = d + k;
        int e = (dk < 32) ? __shfl(ev, half + dk, 64) : __shfl(ev2, half + dk - 32, 64);
        uint2 u = ((const uint2*)(h + (size_t)e * C))[sub];
        uint msk = (dk < cnt) ? 0xffffffffu : 0u;
        u.x &= msk; u.y &= msk;
        s0 += bf_lo(u.x); s1 += bf_hi(u.x); s2 += bf_lo(u.y); s3 += bf_hi(u.y);
      }
    }
    float sc = 1.f / (float)max(truecnt, 1);
    ushort4 o = {(ushort)f2bf(s0 * sc), (ushort)f2bf(s1 * sc),
                 (ushort)f2bf(s2 * sc), (ushort)f2bf(s3 * sc)};
    *(ushort4*)(smean + nl * LDSPAD + sub * 4) = o;
    __syncthreads();
    bf16x8 am[4], ah[4];
    int hr = min(mbase + r16, ntgt - 1);
    const ushort* hrow = h + (size_t)hr * C;
#pragma unroll
    for (int kc = 0; kc < 4; ++kc) {
      am[kc] = *(const bf16x8*)(smean + r16 * LDSPAD + kc * 32 + koff);
      ah[kc] = *(const bf16x8*)(hrow + kc * 32 + koff);
    }
    int nbase = wave * 16;
    float bias = bl[nbase + r16];
    f32x4 acc = {bias, bias, bias, bias};
    const ushort* wlrow = Wlb + (size_t)(nbase + r16) * C;
    const ushort* wrrow = Wrb + (size_t)(nbase + r16) * C;
#pragma unroll
    for (int kc = 0; kc < 4; ++kc) {
      bf16x8 wl = *(const bf16x8*)(wlrow + kc * 32 + koff);
      acc = __builtin_amdgcn_mfma_f32_16x16x32_bf16(am[kc], wl, acc, 0, 0, 0);
      bf16x8 wr = *(const bf16x8*)(wrrow + kc * 32 + koff);
      acc = __builtin_amdgcn_mfma_f32_16x16x32_bf16(ah[kc], wr, acc, 0, 0, 0);
    }
#pragma unroll
    for (int r = 0; r < 4; ++r) {
      int row = mbase + quad * 4 + r;
      if (row < ntgt) {
        float v = acc[r];
        if (RELU) v = fmaxf(v, 0.f);
        if (BF16OUT)
          ((ushort*)outp)[(size_t)row * C + nbase + r16] = (ushort)f2bf(v);
        else
          ((float*)outp)[(size_t)row * C + nbase + r16] = v;
      }
    }
  }
}

// ---------------- k_main: prep | bar | bucket+embed | bar | conv1 | bar | conv2 ----------------
__global__ __launch_bounds__(512, 4) void k_main(Params p) {
  __shared__ ushort smean[16 * LDSPAD];
  const int tid = threadIdx.x;
  const int gtid = blockIdx.x * 512 + tid;
  const int gsz = gridDim.x * 512;
  const int nblk = gridDim.x;
  const int W_ELEMS = C * C;
  uint* leaves = p.ctrl;
  uint* rel = p.ctrl + (NLEAF << 6);

  // ---- Phase 0: prep — emb->bf16, weights->bf16, zero cnt arrays ----
  {
    const float4* ef = (const float4*)p.emb;
    ushort4* eo = (ushort4*)p.embh;
    for (int i = gtid; i < p.leafN4; i += gsz) {
      float4 f = ef[i];
      ushort4 o = {(ushort)f2bf(f.x), (ushort)f2bf(f.y), (ushort)f2bf(f.z), (ushort)f2bf(f.w)};
      eo[i] = o;
    }
    int nw4 = W_ELEMS / 4;
    ushort4* wo = (ushort4*)p.wb;
    for (int i = gtid; i < 4 * nw4; i += gsz) {
      int m = i / nw4;
      int j = i - m * nw4;
      const float4* w = (m == 0) ? (const float4*)p.Wl1
                      : (m == 1) ? (const float4*)p.Wr1
                      : (m == 2) ? (const float4*)p.Wl2
                                 : (const float4*)p.Wr2;
      float4 f = w[j];
      ushort4 o = {(ushort)f2bf(f.x), (ushort)f2bf(f.y), (ushort)f2bf(f.z), (ushort)f2bf(f.w)};
      wo[i] = o;
    }
    int4 z = {0, 0, 0, 0};
    for (int i = gtid; i < p.nz4; i += gsz) p.zbase[i] = z;
  }
  grid_barrier(leaves, rel, 0, nblk);

  // ---- Phase 1: padded-CSR bucket (both graphs), then embed+LN+ReLU ----
  {
    int etot = p.e1 + p.e2;
    for (int i = gtid; i < etot; i += gsz) {
      if (i < p.e1) {
        int d = p.dst1[i];
        int pos = atomicAdd(&p.cnt1[d], 1);
        if (pos < CAP) p.slots1[d * CAP + pos] = p.src1[i];
      } else {
        int j = i - p.e1;
        int d = p.dst2[j];
        int pos = atomicAdd(&p.cnt2[d], 1);
        if (pos < CAP) p.slots2[d * CAP + pos] = p.src2[j];
      }
    }
    int lane = tid & 63;
    int grp = lane >> 5, sub = lane & 31;
    int gwave = blockIdx.x * 8 + (tid >> 6);
    int nwaves = nblk * 8;
    for (int node = gwave; node < p.n0; node += nwaves) {
      int xv = p.x[(size_t)node * 16 + (lane & 15)];
      float s0 = 0.f, s1 = 0.f, s2 = 0.f, s3 = 0.f;
#pragma unroll
      for (int w = 0; w < 16; w += 2) {
        int tok = __shfl(xv, w + grp, 64);
        uint2 u = ((const uint2*)(p.embh + (size_t)tok * C))[sub];
        s0 += bf_lo(u.x); s1 += bf_hi(u.x); s2 += bf_lo(u.y); s3 += bf_hi(u.y);
      }
      s0 += __shfl_xor(s0, 32, 64);
      s1 += __shfl_xor(s1, 32, 64);
      s2 += __shfl_xor(s2, 32, 64);
      s3 += __shfl_xor(s3, 32, 64);
      float red = s0 + s1 + s2 + s3;
#pragma unroll
      for (int off = 16; off; off >>= 1) red += __shfl_xor(red, off, 64);
      float mu = red * (1.f / C);
      float c0 = s0 - mu, c1 = s1 - mu, c2 = s2 - mu, c3 = s3 - mu;
      float sq = c0 * c0 + c1 * c1 + c2 * c2 + c3 * c3;
#pragma unroll
      for (int off = 16; off; off >>= 1) sq += __shfl_xor(sq, off, 64);
      float rs = rsqrtf(sq * (1.f / C) + 1e-5f);
      float4 gg = ((const float4*)p.ln_g)[sub];
      float4 bb = ((const float4*)p.ln_b)[sub];
      float o0 = fmaxf(c0 * rs * gg.x + bb.x, 0.f);
      float o1 = fmaxf(c1 * rs * gg.y + bb.y, 0.f);
      float o2 = fmaxf(c2 * rs * gg.z + bb.z, 0.f);
      float o3 = fmaxf(c3 * rs * gg.w + bb.w, 0.f);
      if (grp == 0) {
        ushort4 o = {(ushort)f2bf(o0), (ushort)f2bf(o1), (ushort)f2bf(o2), (ushort)f2bf(o3)};
        ((ushort4*)(p.h0 + (size_t)node * C))[sub] = o;
      }
    }
  }
  grid_barrier(leaves, rel, 1, nblk);

  // ---- Phase 2: conv1 -> h1 (bf16, ReLU) ----
  const int W2 = C * C;
  conv_phase<true, true>(p.cnt1, p.slots1, p.h0, p.wb, p.bl1, p.wb + W2,
                         p.h1, p.n1, smean);
  grid_barrier(leaves, rel, 2, nblk);

  // ---- Phase 3: conv2 -> out (fp32) ----
  conv_phase<false, false>(p.cnt2, p.slots2, p.h1, p.wb + 2 * W2, p.bl2,
                           p.wb + 3 * W2, p.out, p.n2, smean);
}

extern "C" void kernel_launch(void* const* d_in, const int* in_sizes, int n_in,
                              void* d_out, int out_size, void* d_ws, size_t ws_size,
                              hipStream_t stream) {
  Params p;
  p.x    = (const int*)d_in[0];
  p.src1 = (const int*)d_in[1];
  p.dst1 = (const int*)d_in[2];
  p.src2 = (const int*)d_in[3];
  p.dst2 = (const int*)d_in[4];
  p.emb  = (const float*)d_in[7];
  p.ln_g = (const float*)d_in[8];
  p.ln_b = (const float*)d_in[9];
  p.Wl1  = (const float*)d_in[10];
  p.bl1  = (const float*)d_in[11];
  p.Wr1  = (const float*)d_in[12];
  p.Wl2  = (const float*)d_in[13];
  p.bl2  = (const float*)d_in[14];
  p.Wr2  = (const float*)d_in[15];

  p.n0 = in_sizes[0] / 16;   // 100000
  p.e1 = in_sizes[1];        // 500000
  p.e2 = in_sizes[3];        // 100000
  p.n1 = 25000;
  p.n2 = 5000;
  const int leafElems = in_sizes[7];  // 50000*128
  p.leafN4 = leafElems / 4;
  const int W_ELEMS = C * C;

  char* ws = (char*)d_ws;
  size_t off = 0;
  auto alloc = [&](size_t bytes) {
    char* ptr = ws + off;
    off += (bytes + 255) & ~(size_t)255;
    return ptr;
  };
  p.embh   = (ushort*)alloc((size_t)leafElems * 2);     // 12.8 MB
  p.h0     = (ushort*)alloc((size_t)p.n0 * C * 2);      // 25.6 MB
  p.h1     = (ushort*)alloc((size_t)p.n1 * C * 2);      //  6.4 MB
  p.wb     = (ushort*)alloc((size_t)4 * W_ELEMS * 2);   // Wl1|Wr1|Wl2|Wr2
  p.slots1 = (int*)alloc((size_t)p.n1 * CAP * 4);       //  6.4 MB
  p.slots2 = (int*)alloc((size_t)p.n2 * CAP * 4);       //  1.28 MB
  char* zbase = ws + off;  // zeroed by phase 0
  p.cnt1   = (int*)alloc((size_t)p.n1 * 4);
  p.cnt2   = (int*)alloc((size_t)p.n2 * 4);
  size_t zbytes = (size_t)((ws + off) - zbase);
  p.zbase = (int4*)zbase;
  p.nz4 = (int)(zbytes / 16);
  p.ctrl = (uint*)alloc((size_t)(NLEAF + 1) * 64 * 4);  // leaves + rel
  p.out = (float*)d_out;

  // zero barrier counters (cnt arrays are zeroed by phase 0 inside the kernel)
  (void)hipMemsetAsync(p.ctrl, 0, (size_t)(NLEAF + 1) * 64 * 4, stream);

  int maxBlk = 0;
  hipError_t e = hipOccupancyMaxActiveBlocksPerMultiprocessor(&maxBlk, k_main, 512, 0);
  if (e != hipSuccess || maxBlk < 1) maxBlk = 1;
  int nblk = maxBlk * 256;   // 256 CUs on MI355X
  if (nblk > 1024) nblk = 1024;
  void* args[] = {&p};
  hipLaunchCooperativeKernel((void*)k_main, dim3(nblk), dim3(512), args, 0, stream);
}